// Round 1
// baseline (308.331 us; speedup 1.0000x reference)
//
#include <hip/hip_runtime.h>
#include <hip/hip_bf16.h>

#define Nn 16384
#define Dd 256

typedef __attribute__((ext_vector_type(8))) short short8;
typedef __attribute__((ext_vector_type(4))) float float4v;

__device__ inline unsigned short f2bf(float f) {
    unsigned u = __builtin_bit_cast(unsigned, f);
    u += 0x7fffu + ((u >> 16) & 1u);   // round-to-nearest-even
    return (unsigned short)(u >> 16);
}

__device__ inline void gload_lds16(const void* g, void* l) {
    __builtin_amdgcn_global_load_lds(
        (const __attribute__((address_space(1))) void*)g,
        (__attribute__((address_space(3))) void*)l, 16, 0, 0);
}

// fp32 -> bf16 conversion pre-pass: each thread converts one float4 of A and B
__global__ __launch_bounds__(256) void cvt_kernel(
        const float4* __restrict__ a, const float4* __restrict__ b,
        ushort4* __restrict__ oa, ushort4* __restrict__ ob) {
    int i = blockIdx.x * 256 + threadIdx.x;
    float4 va = a[i];
    float4 vb = b[i];
    oa[i] = make_ushort4(f2bf(va.x), f2bf(va.y), f2bf(va.z), f2bf(va.w));
    ob[i] = make_ushort4(f2bf(vb.x), f2bf(vb.y), f2bf(vb.z), f2bf(vb.w));
}

// Fused bf16 GEMM (sim = za . zb^T) + siglip loss + global reduction.
// 128x128 tile, BK=64, 4 waves (each computes 64x64 via 4x4 fragments of 16x16x32).
__global__ __launch_bounds__(256) void siglip_kernel(
        const unsigned short* __restrict__ ga,   // za bf16 [16384][256]
        const unsigned short* __restrict__ gb,   // zb bf16 [16384][256]
        const float* __restrict__ bp,            // bias scalar
        float* __restrict__ out) {
    __shared__ unsigned short As[128 * 64];
    __shared__ unsigned short Bs[128 * 64];

    const int tid  = threadIdx.x;
    const int lane = tid & 63;
    const int wid  = tid >> 6;
    const int wm   = wid >> 1;     // wave row (0..1)
    const int wn   = wid & 1;      // wave col (0..1)
    const int bx   = blockIdx.x;   // col tile
    const int by   = blockIdx.y;   // row tile
    const size_t rowA0 = (size_t)by * 128;
    const size_t rowB0 = (size_t)bx * 128;

    const int r  = lane & 15;   // fragment row/col within 16
    const int hk = lane >> 4;   // k-subchunk 0..3 (8 bf16 each)

    float4v acc[4][4];
#pragma unroll
    for (int m = 0; m < 4; ++m)
#pragma unroll
        for (int n = 0; n < 4; ++n)
            acc[m][n] = (float4v){0.f, 0.f, 0.f, 0.f};

#pragma unroll 1
    for (int kt = 0; kt < 4; ++kt) {
        const int k0 = kt * 64;
        // ---- stage 128x64 bf16 tiles of A and B via global_load_lds (16B) ----
        // LDS is linear in chunk index c; the global SOURCE column is
        // pre-swizzled (col8 ^ (row&7)) so that reads below can XOR-deswizzle
        // -> bank-conflict-free ds_read_b128 (rule #21: both-sides-or-neither).
#pragma unroll
        for (int p = 0; p < 4; ++p) {
            int c    = p * 256 + tid;
            int row  = c >> 3;
            int scol = (c & 7) ^ (row & 7);
            size_t goffA = (rowA0 + row) * Dd + k0 + scol * 8;
            size_t goffB = (rowB0 + row) * Dd + k0 + scol * 8;
            gload_lds16(ga + goffA, &As[c * 8]);
            gload_lds16(gb + goffB, &Bs[c * 8]);
        }
        __syncthreads();

        // ---- compute: 2 K-steps of 32, 4x4 fragments ----
#pragma unroll
        for (int s = 0; s < 2; ++s) {
            short8 aF[4], bF[4];
#pragma unroll
            for (int m = 0; m < 4; ++m) {
                int rr = wm * 64 + m * 16 + r;
                int ch = (s * 4 + hk) ^ (rr & 7);
                aF[m] = *(const short8*)&As[rr * 64 + ch * 8];
            }
#pragma unroll
            for (int n = 0; n < 4; ++n) {
                int rr = wn * 64 + n * 16 + r;
                int ch = (s * 4 + hk) ^ (rr & 7);
                bF[n] = *(const short8*)&Bs[rr * 64 + ch * 8];
            }
#pragma unroll
            for (int m = 0; m < 4; ++m)
#pragma unroll
                for (int n = 0; n < 4; ++n)
                    acc[m][n] = __builtin_amdgcn_mfma_f32_16x16x32_bf16(
                        aF[m], bF[n], acc[m][n], 0, 0, 0);
        }
        __syncthreads();
    }

    // ---- epilogue: loss = softplus(-(t*sim + bias)), accumulate ----
    const float bias = *bp;
    float lsum = 0.f;
    const int r4 = hk * 4;
#pragma unroll
    for (int m = 0; m < 4; ++m) {
        int ib = by * 128 + wm * 64 + m * 16 + r4;
#pragma unroll
        for (int n = 0; n < 4; ++n) {
            int j = bx * 128 + wn * 64 + n * 16 + r;
#pragma unroll
            for (int q = 0; q < 4; ++q) {
                int i = ib + q;
                float s = acc[m][n][q];
                float x = (i == j) ? (s + bias) : (bias - s);  // t*sim + bias
                float y = -x;                                   // softplus(-x)
                float e = __expf(-fabsf(y));
                lsum += fmaxf(y, 0.f) + __logf(1.f + e);
            }
        }
    }

    // wave reduction (64 lanes)
#pragma unroll
    for (int off = 32; off; off >>= 1)
        lsum += __shfl_down(lsum, off);

    __shared__ float wsum[4];
    if (lane == 0) wsum[wid] = lsum;
    __syncthreads();
    if (tid == 0) {
        float t = (wsum[0] + wsum[1] + wsum[2] + wsum[3]) *
                  (1.0f / ((float)Nn * (float)Nn));
        atomicAdd(out, t);
    }
}

extern "C" void kernel_launch(void* const* d_in, const int* in_sizes, int n_in,
                              void* d_out, int out_size, void* d_ws, size_t ws_size,
                              hipStream_t stream) {
    const float* za   = (const float*)d_in[0];
    const float* zb   = (const float*)d_in[1];
    const float* bias = (const float*)d_in[2];

    unsigned short* wa = (unsigned short*)d_ws;
    unsigned short* wb = wa + (size_t)Nn * Dd;

    // zero the output accumulator (harness does not re-poison between replays)
    hipMemsetAsync(d_out, 0, sizeof(float), stream);

    // fp32 -> bf16 pre-pass
    cvt_kernel<<<dim3(Nn * Dd / 1024), 256, 0, stream>>>(
        (const float4*)za, (const float4*)zb, (ushort4*)wa, (ushort4*)wb);

    // fused GEMM + loss
    dim3 grid(Nn / 128, Nn / 128);
    siglip_kernel<<<grid, 256, 0, stream>>>(wa, wb, bias, (float*)d_out);
}

// Round 2
// 183.341 us; speedup vs baseline: 1.6817x; 1.6817x over previous
//
#include <hip/hip_runtime.h>
#include <hip/hip_bf16.h>

#define Nn 16384
#define Dd 256
#define L2E 1.4426950408889634f
#define LN2 0.6931471805599453f

typedef __attribute__((ext_vector_type(8))) short short8;
typedef __attribute__((ext_vector_type(4))) float float4v;

__device__ inline unsigned short f2bf(float f) {
    unsigned u = __builtin_bit_cast(unsigned, f);
    u += 0x7fffu + ((u >> 16) & 1u);   // round-to-nearest-even
    return (unsigned short)(u >> 16);
}

__device__ inline void gload_lds16(const void* g, void* l) {
    __builtin_amdgcn_global_load_lds(
        (const __attribute__((address_space(1))) void*)g,
        (__attribute__((address_space(3))) void*)l, 16, 0, 0);
}

// fp32 -> bf16 pre-pass. z_a is pre-scaled by log2(e) so the epilogue's
// softplus works directly in the log2/exp2 domain (no per-element muls).
__global__ __launch_bounds__(256) void cvt_kernel(
        const float4* __restrict__ a, const float4* __restrict__ b,
        ushort4* __restrict__ oa, ushort4* __restrict__ ob) {
    int i = blockIdx.x * 256 + threadIdx.x;
    float4 va = a[i];
    float4 vb = b[i];
    oa[i] = make_ushort4(f2bf(va.x * L2E), f2bf(va.y * L2E),
                         f2bf(va.z * L2E), f2bf(va.w * L2E));
    ob[i] = make_ushort4(f2bf(vb.x), f2bf(vb.y), f2bf(vb.z), f2bf(vb.w));
}

// Fused bf16 GEMM (sim' = log2e * za.zb^T) + siglip loss + reduction.
// 256x256 tile, BK=64, 512 threads = 8 waves (2M x 4N), each wave 128x64 out.
// Double-buffered LDS (128KB), raw s_barrier + counted vmcnt prefetch.
__global__ __launch_bounds__(512, 2) void siglip_kernel(
        const unsigned short* __restrict__ ga,   // za*log2e bf16 [16384][256]
        const unsigned short* __restrict__ gb,   // zb bf16 [16384][256]
        const float* __restrict__ bp,            // bias scalar
        float* __restrict__ out) {
    __shared__ unsigned short As[2][256 * 64];
    __shared__ unsigned short Bs[2][256 * 64];
    __shared__ float wsum[8];

    const int tid  = threadIdx.x;
    const int lane = tid & 63;
    const int wid  = tid >> 6;
    const int wm   = wid >> 2;     // wave row (0..1) -> 128 rows
    const int wn   = wid & 3;      // wave col (0..3) -> 64 cols

    // Block swizzle: XCD-chunked (8 XCDs x 512 blocks) + 8x8 supertile so a
    // supertile's A+B panels (2MB) fit one XCD's 4MB L2.
    const int bid  = blockIdx.x;
    const int nid  = (bid & 7) * 512 + (bid >> 3);   // bijective, 4096%8==0
    const int sid  = nid >> 6;
    const int sloc = nid & 63;
    const int by   = (sid >> 3) * 8 + (sloc >> 3);
    const int bx   = (sid & 7) * 8 + (sloc & 7);

    const size_t rowA0 = (size_t)by * 256;
    const size_t rowB0 = (size_t)bx * 256;

    const int r  = lane & 15;   // fragment col within 16
    const int hk = lane >> 4;   // k-subchunk 0..3 (8 bf16 each)

    float4v acc[8][4];
#pragma unroll
    for (int m = 0; m < 8; ++m)
#pragma unroll
        for (int n = 0; n < 4; ++n)
            acc[m][n] = (float4v){0.f, 0.f, 0.f, 0.f};

    // LDS linear in chunk index; global SOURCE column pre-swizzled
    // (col8 ^ (row&7)) so ds_read_b128 below is bank-conflict-free (rule #21).
#define STAGE(BUF, K0)                                                        \
    {                                                                         \
        _Pragma("unroll")                                                     \
        for (int p = 0; p < 4; ++p) {                                         \
            int c    = p * 512 + tid;                                         \
            int row  = c >> 3;                                                \
            int scol = (c & 7) ^ (row & 7);                                   \
            gload_lds16(&ga[(rowA0 + row) * Dd + (K0) + scol * 8],            \
                        &As[BUF][c * 8]);                                     \
            gload_lds16(&gb[(rowB0 + row) * Dd + (K0) + scol * 8],            \
                        &Bs[BUF][c * 8]);                                     \
        }                                                                     \
    }

#define COMPUTE(BUF)                                                          \
    {                                                                         \
        _Pragma("unroll")                                                     \
        for (int s = 0; s < 2; ++s) {                                         \
            short8 aF[8], bF[4];                                              \
            _Pragma("unroll")                                                 \
            for (int m = 0; m < 8; ++m) {                                     \
                int rr = wm * 128 + m * 16 + r;                               \
                int ch = (s * 4 + hk) ^ (rr & 7);                             \
                aF[m] = *(const short8*)&As[BUF][rr * 64 + ch * 8];           \
            }                                                                 \
            _Pragma("unroll")                                                 \
            for (int n = 0; n < 4; ++n) {                                     \
                int rr = wn * 64 + n * 16 + r;                                \
                int ch = (s * 4 + hk) ^ (rr & 7);                             \
                bF[n] = *(const short8*)&Bs[BUF][rr * 64 + ch * 8];           \
            }                                                                 \
            _Pragma("unroll")                                                 \
            for (int m = 0; m < 8; ++m)                                       \
                _Pragma("unroll")                                             \
                for (int n = 0; n < 4; ++n)                                   \
                    acc[m][n] = __builtin_amdgcn_mfma_f32_16x16x32_bf16(      \
                        aF[m], bF[n], acc[m][n], 0, 0, 0);                    \
        }                                                                     \
    }

    // ---- pipelined K loop (K=256, 4 tiles of 64), double-buffered ----
    STAGE(0, 0)
    STAGE(1, 64)
    asm volatile("s_waitcnt vmcnt(8)" ::: "memory");  // tile0 landed
    __builtin_amdgcn_s_barrier();
    COMPUTE(0)
    __builtin_amdgcn_s_barrier();
    STAGE(0, 128)
    asm volatile("s_waitcnt vmcnt(8)" ::: "memory");  // tile1 landed
    __builtin_amdgcn_s_barrier();
    COMPUTE(1)
    __builtin_amdgcn_s_barrier();
    STAGE(1, 192)
    asm volatile("s_waitcnt vmcnt(8)" ::: "memory");  // tile2 landed
    __builtin_amdgcn_s_barrier();
    COMPUTE(0)
    __builtin_amdgcn_s_barrier();
    asm volatile("s_waitcnt vmcnt(0)" ::: "memory");  // tile3 landed
    __builtin_amdgcn_s_barrier();
    COMPUTE(1)

    // ---- epilogue ----
    // acc holds s' = s*log2e. Off-diag logit loss = softplus(s - bias)
    //   = ln2 * [ max(y,0) + log2(1 + 2^(-|y|)) ],  y = s' - bias*log2e.
    const float bias2 = (*bp) * L2E;
    float lsum = 0.f;
#pragma unroll
    for (int m = 0; m < 8; ++m)
#pragma unroll
        for (int n = 0; n < 4; ++n) {
            float4v a = acc[m][n];
#pragma unroll
            for (int q = 0; q < 4; ++q) {
                float y = a[q] - bias2;
                float e = __builtin_amdgcn_exp2f(-fabsf(y));
                float l = __builtin_amdgcn_logf(1.f + e);
                lsum += fmaxf(y, 0.f) + l;
            }
        }

    // Diagonal correction: only on the 64 bx==by blocks, replace the
    // off-diag term with softplus(-(s+bias)).
    if (bx == by) {
#pragma unroll
        for (int m = 0; m < 8; ++m)
#pragma unroll
            for (int n = 0; n < 4; ++n)
#pragma unroll
                for (int q = 0; q < 4; ++q) {
                    int i_loc = wm * 128 + m * 16 + hk * 4 + q;
                    int j_loc = wn * 64 + n * 16 + r;
                    if (i_loc == j_loc) {
                        float sv = acc[m][n][q];
                        float y  = sv - bias2;
                        float u  = -(sv + bias2);
                        float off = fmaxf(y, 0.f) +
                            __builtin_amdgcn_logf(1.f + __builtin_amdgcn_exp2f(-fabsf(y)));
                        float dg  = fmaxf(u, 0.f) +
                            __builtin_amdgcn_logf(1.f + __builtin_amdgcn_exp2f(-fabsf(u)));
                        lsum += dg - off;
                    }
                }
    }

    // wave reduction (64 lanes) then block reduction
#pragma unroll
    for (int off = 32; off; off >>= 1)
        lsum += __shfl_down(lsum, off);
    if (lane == 0) wsum[wid] = lsum;
    __syncthreads();
    if (tid == 0) {
        float t = 0.f;
#pragma unroll
        for (int w = 0; w < 8; ++w) t += wsum[w];
        atomicAdd(out, t * (LN2 / ((float)Nn * (float)Nn)));
    }
#undef STAGE
#undef COMPUTE
}

extern "C" void kernel_launch(void* const* d_in, const int* in_sizes, int n_in,
                              void* d_out, int out_size, void* d_ws, size_t ws_size,
                              hipStream_t stream) {
    const float* za   = (const float*)d_in[0];
    const float* zb   = (const float*)d_in[1];
    const float* bias = (const float*)d_in[2];

    unsigned short* wa = (unsigned short*)d_ws;
    unsigned short* wb = wa + (size_t)Nn * Dd;

    // zero the output accumulator (harness does not re-poison between replays)
    hipMemsetAsync(d_out, 0, sizeof(float), stream);

    // fp32 -> bf16 pre-pass (A pre-scaled by log2e)
    cvt_kernel<<<dim3(Nn * Dd / 1024), 256, 0, stream>>>(
        (const float4*)za, (const float4*)zb, (ushort4*)wa, (ushort4*)wb);

    // fused GEMM + loss
    siglip_kernel<<<dim3(4096), 512, 0, stream>>>(wa, wb, bias, (float*)d_out);
}